// Round 2
// baseline (1340.744 us; speedup 1.0000x reference)
//
#include <hip/hip_runtime.h>
#include <hip/hip_bf16.h>

typedef float f32x4 __attribute__((ext_vector_type(4)));
typedef __bf16 bf16x8 __attribute__((ext_vector_type(8)));

#define B_SZ 2048
#define IN_SZ 2048
#define H_SZ 1024
#define G_SZ (4 * H_SZ)   // 4096
#define T_STEPS 15
#define INIT_ST 0.01f

__device__ __forceinline__ float sigmoid_f(float x) { return 1.0f / (1.0f + __expf(-x)); }
__device__ __forceinline__ float tanh_f(float x)    { return 1.0f - 2.0f / (__expf(2.0f * x) + 1.0f); }

// fp32x8 -> bf16 hi + bf16 lo (Markidis split)
__device__ __forceinline__ void split8(f32x4 v0, f32x4 v1, bf16x8* h, bf16x8* l) {
  bf16x8 hv, lv;
  #pragma unroll
  for (int j = 0; j < 4; ++j) {
    float f = v0[j];
    __bf16 hb = (__bf16)f;
    hv[j] = hb;
    lv[j] = (__bf16)(f - (float)hb);
  }
  #pragma unroll
  for (int j = 0; j < 4; ++j) {
    float f = v1[j];
    __bf16 hb = (__bf16)f;
    hv[4 + j] = hb;
    lv[4 + j] = (__bf16)(f - (float)hb);
  }
  *h = hv;
  *l = lv;
}

// async global -> LDS, 16 bytes/lane. LDS dest = wave-uniform base + lane*16.
__device__ __forceinline__ void gl16(const bf16x8* src, bf16x8* lds_base_uniform) {
  __builtin_amdgcn_global_load_lds(
      (const __attribute__((address_space(1))) void*)src,
      (__attribute__((address_space(3))) void*)lds_base_uniform, 16, 0, 0);
}

// ---------------------------------------------------------------------------
// Repack W_hh (fp32 [4096][1024]) -> bf16 hi/lo chunks in staged-tile order:
//   flat chunk index  cid = ((g*16 + nt)*32 + ks)*256 + s
//   s encodes row = s>>2, kc = (s&3) ^ (row&3)   (the LDS bank swizzle)
//   source element = Whh[(g*1024 + nt*64 + row)*1024 + ks*32 + kc*8 + e]
// ---------------------------------------------------------------------------
__global__ __launch_bounds__(256)
void repack_whh(const float* __restrict__ Whh, bf16x8* __restrict__ Wh, bf16x8* __restrict__ Wl)
{
  int cid = blockIdx.x * 256 + threadIdx.x;     // 0 .. 524287
  int s    = cid & 255;
  int rest = cid >> 8;        // (g*16+nt)*32 + ks
  int ks   = rest & 31;
  int gnt  = rest >> 5;       // g*16 + nt  (0..63)
  int row  = s >> 2;
  int kc   = (s & 3) ^ (row & 3);
  const float* src = Whh + (size_t)(gnt * 64 + row) * H_SZ + ks * 32 + kc * 8;
  bf16x8 h, l;
  split8(*(const f32x4*)src, *(const f32x4*)(src + 4), &h, &l);
  Wh[cid] = h;
  Wl[cid] = l;
}

// h0 = 0.01 everywhere, pre-split (layout-independent since constant)
__global__ __launch_bounds__(256)
void init_h0(bf16x8* __restrict__ hh, bf16x8* __restrict__ hl)
{
  int cid = blockIdx.x * 256 + threadIdx.x;     // 0 .. 262143
  __bf16 hi = (__bf16)INIT_ST;
  __bf16 lo = (__bf16)(INIT_ST - (float)hi);
  bf16x8 h, l;
  #pragma unroll
  for (int j = 0; j < 8; ++j) { h[j] = hi; l[j] = lo; }
  hh[cid] = h;
  hl[cid] = l;
}

// ---------------------------------------------------------------------------
// xg = x @ W_ih^T + b_ih + b_hh   (both biases folded here)
// Unchanged 128x128 structure from round 1 (proven).
// ---------------------------------------------------------------------------
__global__ __launch_bounds__(256, 2)
void xg_gemm(const float* __restrict__ x, const float* __restrict__ Wih,
             const float* __restrict__ bih, const float* __restrict__ bhh,
             float* __restrict__ xg)
{
  __shared__ bf16x8 Ah[128 * 4], Al[128 * 4], Bh[128 * 4], Bl[128 * 4];
  const int tid  = threadIdx.x;
  const int lane = tid & 63;
  const int wv   = tid >> 6;
  const int wm   = wv >> 1, wn = wv & 1;
  const int bm   = blockIdx.y * 128;
  const int bn   = blockIdx.x * 128;

  f32x4 acc[4][4] = {};

  for (int k0 = 0; k0 < IN_SZ; k0 += 32) {
    #pragma unroll
    for (int c = 0; c < 2; ++c) {
      int cid = tid + c * 256;
      int row = cid >> 2, kc = cid & 3;
      int idx = row * 4 + (kc ^ (row & 3));
      const float* srcA = x + (size_t)(bm + row) * IN_SZ + k0 + kc * 8;
      split8(*(const f32x4*)srcA, *(const f32x4*)(srcA + 4), &Ah[idx], &Al[idx]);
      const float* srcB = Wih + (size_t)(bn + row) * IN_SZ + k0 + kc * 8;
      split8(*(const f32x4*)srcB, *(const f32x4*)(srcB + 4), &Bh[idx], &Bl[idx]);
    }
    __syncthreads();

    const int kc = lane >> 4;
    bf16x8 ah[4], al[4], bh[4], bl[4];
    #pragma unroll
    for (int i = 0; i < 4; ++i) {
      int ra = wm * 64 + i * 16 + (lane & 15);
      int ia = ra * 4 + (kc ^ (ra & 3));
      ah[i] = Ah[ia]; al[i] = Al[ia];
      int rb = wn * 64 + i * 16 + (lane & 15);
      int ib = rb * 4 + (kc ^ (rb & 3));
      bh[i] = Bh[ib]; bl[i] = Bl[ib];
    }
    #pragma unroll
    for (int i = 0; i < 4; ++i)
      #pragma unroll
      for (int j = 0; j < 4; ++j) {
        acc[i][j] = __builtin_amdgcn_mfma_f32_16x16x32_bf16(ah[i], bh[j], acc[i][j], 0, 0, 0);
        acc[i][j] = __builtin_amdgcn_mfma_f32_16x16x32_bf16(ah[i], bl[j], acc[i][j], 0, 0, 0);
        acc[i][j] = __builtin_amdgcn_mfma_f32_16x16x32_bf16(al[i], bh[j], acc[i][j], 0, 0, 0);
      }
    __syncthreads();
  }

  #pragma unroll
  for (int i = 0; i < 4; ++i) {
    int m0 = bm + wm * 64 + i * 16 + ((lane >> 4) * 4);
    #pragma unroll
    for (int j = 0; j < 4; ++j) {
      int n = bn + wn * 64 + j * 16 + (lane & 15);
      float bb = bih[n] + bhh[n];
      #pragma unroll
      for (int r = 0; r < 4; ++r)
        xg[(size_t)(m0 + r) * G_SZ + n] = acc[i][j][r] + bb;
    }
  }
}

// ---------------------------------------------------------------------------
// Fused LSTM step. Pre-split weights + pre-split h; global_load_lds staging;
// 2-phase double-buffered K-loop (1 barrier / K-step).
// Grid 512 blocks, XCD-remapped: each XCD owns 2 hidden-col tiles (W slice
// stays L2-resident), all 32 batch tiles.
// ---------------------------------------------------------------------------
__global__ __launch_bounds__(256, 2)
void lstm_step(const bf16x8* __restrict__ hsh,  // h_prev split hi (A-layout)
               const bf16x8* __restrict__ hsl,  // h_prev split lo
               const bf16x8* __restrict__ Wh,   // W_hh split hi (repacked)
               const bf16x8* __restrict__ Wl,   // W_hh split lo
               const float* __restrict__ xg,    // [2048][4096], biases folded
               float* __restrict__ cst,         // [2048][1024]
               float* __restrict__ hout,        // fp32 out slice
               bf16x8* __restrict__ hnh,        // next-step h split hi
               bf16x8* __restrict__ hnl,        // next-step h split lo
               int first)
{
  __shared__ bf16x8 Ah[2][256], Al[2][256];
  __shared__ bf16x8 Bh[2][4][256], Bl[2][4][256];

  const int tid  = threadIdx.x;
  const int lane = tid & 63;
  const int wv   = tid >> 6;
  const int wm   = wv >> 1, wn = wv & 1;

  // XCD-aware remap (512 % 8 == 0 -> bijective)
  const int bid = blockIdx.x;
  const int wg  = (bid & 7) * 64 + (bid >> 3);
  const int nt  = wg >> 5;          // hidden-col tile 0..15
  const int mt  = wg & 31;          // batch tile 0..31
  const int bm  = mt * 64;
  const int bn  = nt * 64;

  f32x4 acc[4][2][2] = {};          // [gate][mi][ni]

#define STAGE(buf, ks)                                                        \
  do {                                                                        \
    const bf16x8* a_h = hsh + ((size_t)mt * 32 + (ks)) * 256;                 \
    const bf16x8* a_l = hsl + ((size_t)mt * 32 + (ks)) * 256;                 \
    gl16(a_h + wv * 64 + lane, &Ah[buf][wv * 64]);                            \
    gl16(a_l + wv * 64 + lane, &Al[buf][wv * 64]);                            \
    _Pragma("unroll")                                                         \
    for (int g = 0; g < 4; ++g) {                                             \
      size_t roff = ((size_t)(g * 16 + nt) * 32 + (ks)) * 256;                \
      gl16(Wh + roff + wv * 64 + lane, &Bh[buf][g][wv * 64]);                 \
      gl16(Wl + roff + wv * 64 + lane, &Bl[buf][g][wv * 64]);                 \
    }                                                                         \
  } while (0)

  STAGE(0, 0);
  __syncthreads();

  int cur = 0;
  for (int ks = 0; ks < 32; ++ks) {
    if (ks < 31) STAGE(cur ^ 1, ks + 1);

    const int kc = lane >> 4;
    bf16x8 ah[2], al[2];
    #pragma unroll
    for (int mi = 0; mi < 2; ++mi) {
      int r  = wm * 32 + mi * 16 + (lane & 15);
      int ia = r * 4 + (kc ^ (r & 3));
      ah[mi] = Ah[cur][ia]; al[mi] = Al[cur][ia];
    }
    bf16x8 bh[4][2], bl[4][2];
    #pragma unroll
    for (int g = 0; g < 4; ++g)
      #pragma unroll
      for (int ni = 0; ni < 2; ++ni) {
        int r  = wn * 32 + ni * 16 + (lane & 15);
        int ib = r * 4 + (kc ^ (r & 3));
        bh[g][ni] = Bh[cur][g][ib]; bl[g][ni] = Bl[cur][g][ib];
      }
    #pragma unroll
    for (int g = 0; g < 4; ++g)
      #pragma unroll
      for (int mi = 0; mi < 2; ++mi)
        #pragma unroll
        for (int ni = 0; ni < 2; ++ni) {
          acc[g][mi][ni] = __builtin_amdgcn_mfma_f32_16x16x32_bf16(ah[mi], bh[g][ni], acc[g][mi][ni], 0, 0, 0);
          acc[g][mi][ni] = __builtin_amdgcn_mfma_f32_16x16x32_bf16(ah[mi], bl[g][ni], acc[g][mi][ni], 0, 0, 0);
          acc[g][mi][ni] = __builtin_amdgcn_mfma_f32_16x16x32_bf16(al[mi], bh[g][ni], acc[g][mi][ni], 0, 0, 0);
        }
    __syncthreads();   // drains vmcnt (next buffer staged) + lgkm (reads done)
    cur ^= 1;
  }
#undef STAGE

  // fused LSTM epilogue + producer-side split of h for next step
  #pragma unroll
  for (int mi = 0; mi < 2; ++mi) {
    #pragma unroll
    for (int ni = 0; ni < 2; ++ni) {
      int n = bn + wn * 32 + ni * 16 + (lane & 15);
      int ks2 = n >> 5;
      int kc2 = (n >> 3) & 3;
      int e   = n & 7;
      #pragma unroll
      for (int r = 0; r < 4; ++r) {
        int m = bm + wm * 32 + mi * 16 + ((lane >> 4) * 4) + r;
        const float* xr = xg + (size_t)m * G_SZ;
        float pi = acc[0][mi][ni][r] + xr[n];
        float pf = acc[1][mi][ni][r] + xr[H_SZ + n];
        float pg = acc[2][mi][ni][r] + xr[2 * H_SZ + n];
        float po = acc[3][mi][ni][r] + xr[3 * H_SZ + n];
        float iv = sigmoid_f(pi);
        float fv = sigmoid_f(pf);
        float gv = tanh_f(pg);
        float ov = sigmoid_f(po);
        size_t off = (size_t)m * H_SZ + n;
        float cold = first ? INIT_ST : cst[off];
        float cnew = fv * cold + iv * gv;
        cst[off]  = cnew;
        float hv  = ov * tanh_f(cnew);
        hout[off] = hv;
        // split for next step, A-tile layout
        int row = m & 63;
        int s2  = row * 4 + (kc2 ^ (row & 3));
        size_t ci = (((size_t)(m >> 6) * 32 + ks2) * 256 + s2) * 8 + e;
        __bf16 hb = (__bf16)hv;
        ((__bf16*)hnh)[ci] = hb;
        ((__bf16*)hnl)[ci] = (__bf16)(hv - (float)hb);
      }
    }
  }
}

extern "C" void kernel_launch(void* const* d_in, const int* in_sizes, int n_in,
                              void* d_out, int out_size, void* d_ws, size_t ws_size,
                              hipStream_t stream)
{
  const float* x   = (const float*)d_in[0];
  const float* Wih = (const float*)d_in[1];
  const float* Whh = (const float*)d_in[2];
  const float* bih = (const float*)d_in[3];
  const float* bhh = (const float*)d_in[4];
  float* out = (float*)d_out;

  // ws layout (72 MB total):
  float*  xg  = (float*)d_ws;                              // 32 MB
  float*  cst = xg + (size_t)B_SZ * G_SZ;                  //  8 MB
  bf16x8* Wh  = (bf16x8*)(cst + (size_t)B_SZ * H_SZ);      //  8 MB
  bf16x8* Wl  = Wh + 524288;                               //  8 MB
  bf16x8* hAh = Wl + 524288;                               //  4 MB
  bf16x8* hAl = hAh + 262144;                              //  4 MB
  bf16x8* hBh = hAl + 262144;                              //  4 MB
  bf16x8* hBl = hBh + 262144;                              //  4 MB

  repack_whh<<<2048, 256, 0, stream>>>(Whh, Wh, Wl);
  init_h0<<<1024, 256, 0, stream>>>(hAh, hAl);
  xg_gemm<<<dim3(G_SZ / 128, B_SZ / 128), 256, 0, stream>>>(x, Wih, bih, bhh, xg);

  for (int t = 0; t < T_STEPS; ++t) {
    const bf16x8* rh = (t & 1) ? hBh : hAh;
    const bf16x8* rl = (t & 1) ? hBl : hAl;
    bf16x8* wh = (t & 1) ? hAh : hBh;
    bf16x8* wl = (t & 1) ? hAl : hBl;
    lstm_step<<<512, 256, 0, stream>>>(rh, rl, Wh, Wl, xg, cst,
                                       out + (size_t)t * B_SZ * H_SZ, wh, wl,
                                       t == 0 ? 1 : 0);
  }
}

// Round 5
// 1045.031 us; speedup vs baseline: 1.2830x; 1.2830x over previous
//
#include <hip/hip_runtime.h>
#include <hip/hip_bf16.h>

typedef float f32x4 __attribute__((ext_vector_type(4)));
typedef __bf16 bf16x8 __attribute__((ext_vector_type(8)));

#define B_SZ 2048
#define IN_SZ 2048
#define H_SZ 1024
#define G_SZ (4 * H_SZ)   // 4096
#define T_STEPS 15
#define INIT_ST 0.01f

__device__ __forceinline__ float sigmoid_f(float x) { return 1.0f / (1.0f + __expf(-x)); }
__device__ __forceinline__ float tanh_f(float x)    { return 1.0f - 2.0f / (__expf(2.0f * x) + 1.0f); }

// fp32x8 -> bf16 hi + bf16 lo (Markidis split)
__device__ __forceinline__ void split8(f32x4 v0, f32x4 v1, bf16x8* h, bf16x8* l) {
  bf16x8 hv, lv;
  #pragma unroll
  for (int j = 0; j < 4; ++j) {
    float f = v0[j];
    __bf16 hb = (__bf16)f;
    hv[j] = hb;
    lv[j] = (__bf16)(f - (float)hb);
  }
  #pragma unroll
  for (int j = 0; j < 4; ++j) {
    float f = v1[j];
    __bf16 hb = (__bf16)f;
    hv[4 + j] = hb;
    lv[4 + j] = (__bf16)(f - (float)hb);
  }
  *h = hv;
  *l = lv;
}

// async global -> LDS, 16 bytes/lane; src per-lane, dest wave-uniform base.
__device__ __forceinline__ void gl16(const bf16x8* src, bf16x8* lds_base_uniform) {
  __builtin_amdgcn_global_load_lds(
      (const __attribute__((address_space(1))) void*)src,
      (__attribute__((address_space(3))) void*)lds_base_uniform, 16, 0, 0);
}

// ---------------------------------------------------------------------------
// Repack W_hh (fp32 [4096][1024]) -> bf16 hi/lo chunks in the B-tile order:
//   cid = ((nt*32 + ks)*1024 + s);  s: row = s>>2 (0..255), kc = (s&3)^(row&3)
//   row: gate = row>>6, col = row&63
//   source = Whh[(gate*1024 + nt*64 + col)*1024 + ks*32 + kc*8 .. +7]
// ---------------------------------------------------------------------------
__global__ __launch_bounds__(256)
void repack_whh(const float* __restrict__ Whh, bf16x8* __restrict__ Wh, bf16x8* __restrict__ Wl)
{
  int cid = blockIdx.x * 256 + threadIdx.x;     // 0 .. 524287
  int s    = cid & 1023;
  int rest = cid >> 10;       // nt*32 + ks
  int ks   = rest & 31;
  int nt   = rest >> 5;       // 0..15
  int row  = s >> 2;          // 0..255
  int kc   = (s & 3) ^ (row & 3);
  int gate = row >> 6, col = row & 63;
  const float* src = Whh + (size_t)(gate * H_SZ + nt * 64 + col) * H_SZ + ks * 32 + kc * 8;
  bf16x8 h, l;
  split8(*(const f32x4*)src, *(const f32x4*)(src + 4), &h, &l);
  Wh[cid] = h;
  Wl[cid] = l;
}

// h0 = 0.01 everywhere, pre-split (layout-independent since constant)
__global__ __launch_bounds__(256)
void init_h0(bf16x8* __restrict__ hh, bf16x8* __restrict__ hl)
{
  int cid = blockIdx.x * 256 + threadIdx.x;     // 0 .. 262143
  __bf16 hi = (__bf16)INIT_ST;
  __bf16 lo = (__bf16)(INIT_ST - (float)hi);
  bf16x8 h, l;
  #pragma unroll
  for (int j = 0; j < 8; ++j) { h[j] = hi; l[j] = lo; }
  hh[cid] = h;
  hl[cid] = l;
}

// ---------------------------------------------------------------------------
// xg = x @ W_ih^T + b_ih + b_hh   (unchanged from round 2)
// ---------------------------------------------------------------------------
__global__ __launch_bounds__(256, 2)
void xg_gemm(const float* __restrict__ x, const float* __restrict__ Wih,
             const float* __restrict__ bih, const float* __restrict__ bhh,
             float* __restrict__ xg)
{
  __shared__ bf16x8 Ah[128 * 4], Al[128 * 4], Bh[128 * 4], Bl[128 * 4];
  const int tid  = threadIdx.x;
  const int lane = tid & 63;
  const int wv   = tid >> 6;
  const int wm   = wv >> 1, wn = wv & 1;
  const int bm   = blockIdx.y * 128;
  const int bn   = blockIdx.x * 128;

  f32x4 acc[4][4] = {};

  for (int k0 = 0; k0 < IN_SZ; k0 += 32) {
    #pragma unroll
    for (int c = 0; c < 2; ++c) {
      int cid = tid + c * 256;
      int row = cid >> 2, kc = cid & 3;
      int idx = row * 4 + (kc ^ (row & 3));
      const float* srcA = x + (size_t)(bm + row) * IN_SZ + k0 + kc * 8;
      split8(*(const f32x4*)srcA, *(const f32x4*)(srcA + 4), &Ah[idx], &Al[idx]);
      const float* srcB = Wih + (size_t)(bn + row) * IN_SZ + k0 + kc * 8;
      split8(*(const f32x4*)srcB, *(const f32x4*)(srcB + 4), &Bh[idx], &Bl[idx]);
    }
    __syncthreads();

    const int kc = lane >> 4;
    bf16x8 ah[4], al[4], bh[4], bl[4];
    #pragma unroll
    for (int i = 0; i < 4; ++i) {
      int ra = wm * 64 + i * 16 + (lane & 15);
      int ia = ra * 4 + (kc ^ (ra & 3));
      ah[i] = Ah[ia]; al[i] = Al[ia];
      int rb = wn * 64 + i * 16 + (lane & 15);
      int ib = rb * 4 + (kc ^ (rb & 3));
      bh[i] = Bh[ib]; bl[i] = Bl[ib];
    }
    #pragma unroll
    for (int i = 0; i < 4; ++i)
      #pragma unroll
      for (int j = 0; j < 4; ++j) {
        acc[i][j] = __builtin_amdgcn_mfma_f32_16x16x32_bf16(ah[i], bh[j], acc[i][j], 0, 0, 0);
        acc[i][j] = __builtin_amdgcn_mfma_f32_16x16x32_bf16(ah[i], bl[j], acc[i][j], 0, 0, 0);
        acc[i][j] = __builtin_amdgcn_mfma_f32_16x16x32_bf16(al[i], bh[j], acc[i][j], 0, 0, 0);
      }
    __syncthreads();
  }

  #pragma unroll
  for (int i = 0; i < 4; ++i) {
    int m0 = bm + wm * 64 + i * 16 + ((lane >> 4) * 4);
    #pragma unroll
    for (int j = 0; j < 4; ++j) {
      int n = bn + wn * 64 + j * 16 + (lane & 15);
      float bb = bih[n] + bhh[n];
      #pragma unroll
      for (int r = 0; r < 4; ++r)
        xg[(size_t)(m0 + r) * G_SZ + n] = acc[i][j][r] + bb;
    }
  }
}

// ---------------------------------------------------------------------------
// Fused LSTM step, T3+T4 structure:
//   BM=128 batch x (4 gates x 64 cols), BK=32, 512 threads = 8 waves
//   wave (wm = wv>>2, wg = wv&3) computes 64x64 of gate wg.
//   Triple-buffered LDS (3 x 48 KB), counted vmcnt(6), 1 barrier / K-step.
//   Epilogue: cross-wave gate exchange via LDS (reused smem, +4 pad).
// ---------------------------------------------------------------------------
__global__ __launch_bounds__(512, 2)
void lstm_step(const bf16x8* __restrict__ hsh,  // h_prev split hi (A-layout)
               const bf16x8* __restrict__ hsl,  // h_prev split lo
               const bf16x8* __restrict__ Wh,   // W_hh split hi (repacked)
               const bf16x8* __restrict__ Wl,   // W_hh split lo
               const float* __restrict__ xg,    // [2048][4096], biases folded
               float* __restrict__ cst,         // [2048][1024]
               float* __restrict__ hout,        // fp32 out slice
               bf16x8* __restrict__ hnh,        // next-step h split hi
               bf16x8* __restrict__ hnl,        // next-step h split lo
               int first)
{
  __shared__ __attribute__((aligned(16))) char smem[147456];
  bf16x8* AhL = (bf16x8*)smem;            // [3][512]
  bf16x8* AlL = AhL + 3 * 512;            // [3][512]
  bf16x8* BhL = AlL + 3 * 512;            // [3][1024]
  bf16x8* BlL = BhL + 3 * 1024;           // [3][1024]

  const int tid  = threadIdx.x;
  const int lane = tid & 63;
  const int wv   = tid >> 6;
  const int wm   = wv >> 2;        // batch half 0..1
  const int wg   = wv & 3;         // gate 0..3

  // XCD-aware remap: 256 blocks, 32/XCD; nt determined by high bits so each
  // XCD keeps 2 W column-slices (2 MB) L2-resident.
  const int bid  = blockIdx.x;
  const int wgid = (bid & 7) * 32 + (bid >> 3);
  const int nt   = wgid >> 4;      // 0..15 hidden-col tile
  const int mt   = wgid & 15;      // 0..15 batch tile (128 rows)

  f32x4 acc[4][4] = {};
  const size_t abase = (size_t)mt * 32;
  const size_t bbase = (size_t)nt * 32;
  const int kc = lane >> 4;

#define STAGE(BUF, KS)                                                      \
  do {                                                                      \
    const bf16x8* sa_h = hsh + (abase + (KS)) * 512 + wv * 64 + lane;       \
    const bf16x8* sa_l = hsl + (abase + (KS)) * 512 + wv * 64 + lane;       \
    gl16(sa_h, AhL + (BUF) * 512 + wv * 64);                                \
    gl16(sa_l, AlL + (BUF) * 512 + wv * 64);                                \
    const bf16x8* sb_h = Wh + (bbase + (KS)) * 1024 + wv * 128;             \
    const bf16x8* sb_l = Wl + (bbase + (KS)) * 1024 + wv * 128;             \
    gl16(sb_h + lane,      BhL + (BUF) * 1024 + wv * 128);                  \
    gl16(sb_h + 64 + lane, BhL + (BUF) * 1024 + wv * 128 + 64);             \
    gl16(sb_l + lane,      BlL + (BUF) * 1024 + wv * 128);                  \
    gl16(sb_l + 64 + lane, BlL + (BUF) * 1024 + wv * 128 + 64);             \
  } while (0)

#define COMPUTE(BUF)                                                        \
  do {                                                                      \
    bf16x8 ah[4], al[4], bh[4], bl[4];                                      \
    _Pragma("unroll")                                                       \
    for (int i = 0; i < 4; ++i) {                                           \
      int ra = wm * 64 + i * 16 + (lane & 15);                              \
      int ia = (BUF) * 512 + ra * 4 + (kc ^ (ra & 3));                      \
      ah[i] = AhL[ia]; al[i] = AlL[ia];                                     \
      int rb = wg * 64 + i * 16 + (lane & 15);                              \
      int ib = (BUF) * 1024 + rb * 4 + (kc ^ (rb & 3));                     \
      bh[i] = BhL[ib]; bl[i] = BlL[ib];                                     \
    }                                                                       \
    __builtin_amdgcn_s_setprio(1);                                          \
    _Pragma("unroll")                                                       \
    for (int i = 0; i < 4; ++i)                                             \
      _Pragma("unroll")                                                     \
      for (int j = 0; j < 4; ++j) {                                         \
        acc[i][j] = __builtin_amdgcn_mfma_f32_16x16x32_bf16(ah[i], bh[j], acc[i][j], 0, 0, 0); \
        acc[i][j] = __builtin_amdgcn_mfma_f32_16x16x32_bf16(ah[i], bl[j], acc[i][j], 0, 0, 0); \
        acc[i][j] = __builtin_amdgcn_mfma_f32_16x16x32_bf16(al[i], bh[j], acc[i][j], 0, 0, 0); \
      }                                                                     \
    __builtin_amdgcn_s_setprio(0);                                          \
  } while (0)

// one K-step: wait cur loads, sync, issue stage 2-ahead, compute cur
#define KSTEP(CUR, TGT, KST)                                                \
  do {                                                                      \
    asm volatile("s_waitcnt vmcnt(6)" ::: "memory");                        \
    __builtin_amdgcn_s_barrier();                                           \
    STAGE(TGT, KST);                                                        \
    COMPUTE(CUR);                                                           \
  } while (0)

  STAGE(0, 0);
  STAGE(1, 1);

  int ks = 0;
  #pragma unroll 1
  for (int blk = 0; blk < 10; ++blk) {
    KSTEP(0, 2, ks + 2);
    KSTEP(1, 0, ks + 3);
    KSTEP(2, 1, ks + 4);
    ks += 3;
  }
  // ks = 30, 31 peeled (no more staging)
  asm volatile("s_waitcnt vmcnt(6)" ::: "memory");
  __builtin_amdgcn_s_barrier();
  COMPUTE(0);
  asm volatile("s_waitcnt vmcnt(0)" ::: "memory");
  __builtin_amdgcn_s_barrier();
  COMPUTE(1);
  __builtin_amdgcn_s_barrier();    // all reads done -> smem reusable

#undef KSTEP
#undef COMPUTE
#undef STAGE

  // ------------------------- fused epilogue --------------------------------
  const int bm = mt * 128, bn = nt * 64;
  const int nl = (tid & 15) * 4;      // 4 n-cols per thread
  const int ml = (tid >> 4) * 4;      // 4 m-rows per thread

  // prefetch xg (4 gates) and c for this thread's 4x4 block
  f32x4 xgv[4][4], cv[4];
  #pragma unroll
  for (int r = 0; r < 4; ++r) {
    int m = bm + ml + r;
    const float* xr = xg + (size_t)m * G_SZ + bn + nl;
    #pragma unroll
    for (int g = 0; g < 4; ++g) xgv[g][r] = *(const f32x4*)(xr + g * H_SZ);
    if (first) cv[r] = (f32x4){INIT_ST, INIT_ST, INIT_ST, INIT_ST};
    else       cv[r] = *(const f32x4*)(cst + (size_t)m * H_SZ + bn + nl);
  }

  float* pre = (float*)smem;          // [2][128][68] fp32, +4 pad

  // phase 1: gates 0 (i), 1 (f)
  if (wg < 2) {
    #pragma unroll
    for (int i = 0; i < 4; ++i)
      #pragma unroll
      for (int j = 0; j < 4; ++j) {
        int n = j * 16 + (lane & 15);
        #pragma unroll
        for (int r = 0; r < 4; ++r) {
          int m = wm * 64 + i * 16 + ((lane >> 4) * 4) + r;
          pre[(wg * 128 + m) * 68 + n] = acc[i][j][r];
        }
      }
  }
  asm volatile("s_waitcnt lgkmcnt(0)" ::: "memory");
  __builtin_amdgcn_s_barrier();

  f32x4 iv[4], fv[4];
  #pragma unroll
  for (int r = 0; r < 4; ++r) {
    int m = ml + r;
    f32x4 pi = *(const f32x4*)&pre[(0 * 128 + m) * 68 + nl];
    f32x4 pf = *(const f32x4*)&pre[(1 * 128 + m) * 68 + nl];
    #pragma unroll
    for (int j = 0; j < 4; ++j) {
      iv[r][j] = sigmoid_f(pi[j] + xgv[0][r][j]);
      fv[r][j] = sigmoid_f(pf[j] + xgv[1][r][j]);
    }
  }
  __builtin_amdgcn_s_barrier();       // phase-1 reads done before overwrite

  // phase 2: gates 2 (g), 3 (o)
  if (wg >= 2) {
    #pragma unroll
    for (int i = 0; i < 4; ++i)
      #pragma unroll
      for (int j = 0; j < 4; ++j) {
        int n = j * 16 + (lane & 15);
        #pragma unroll
        for (int r = 0; r < 4; ++r) {
          int m = wm * 64 + i * 16 + ((lane >> 4) * 4) + r;
          pre[((wg - 2) * 128 + m) * 68 + n] = acc[i][j][r];
        }
      }
  }
  asm volatile("s_waitcnt lgkmcnt(0)" ::: "memory");
  __builtin_amdgcn_s_barrier();

  __bf16* ph = (__bf16*)hnh;
  __bf16* pl = (__bf16*)hnl;
  #pragma unroll
  for (int r = 0; r < 4; ++r) {
    int m = ml + r;
    f32x4 pg = *(const f32x4*)&pre[(0 * 128 + m) * 68 + nl];
    f32x4 po = *(const f32x4*)&pre[(1 * 128 + m) * 68 + nl];
    f32x4 cnew, hv;
    #pragma unroll
    for (int j = 0; j < 4; ++j) {
      float gv = tanh_f(pg[j] + xgv[2][r][j]);
      float ov = sigmoid_f(po[j] + xgv[3][r][j]);
      cnew[j] = fv[r][j] * cv[r][j] + iv[r][j] * gv;
      hv[j]   = ov * tanh_f(cnew[j]);
    }
    int mg = bm + m;
    *(f32x4*)(cst  + (size_t)mg * H_SZ + bn + nl) = cnew;
    *(f32x4*)(hout + (size_t)mg * H_SZ + bn + nl) = hv;

    // split for next step's A layout (128-row tiles)
    int nglob = bn + nl;
    int ks2 = nglob >> 5;
    int kc2 = (nglob >> 3) & 3;
    int eb  = nglob & 7;                 // 0 or 4
    int s2  = m * 4 + (kc2 ^ (m & 3));
    size_t ci = (((size_t)mt * 32 + ks2) * 512 + s2) * 8 + eb;
    union { __bf16 b[4]; uint2 u; } uh, ul;
    #pragma unroll
    for (int j = 0; j < 4; ++j) {
      __bf16 hb = (__bf16)hv[j];
      uh.b[j] = hb;
      ul.b[j] = (__bf16)(hv[j] - (float)hb);
    }
    *(uint2*)(ph + ci) = uh.u;
    *(uint2*)(pl + ci) = ul.u;
  }
}

extern "C" void kernel_launch(void* const* d_in, const int* in_sizes, int n_in,
                              void* d_out, int out_size, void* d_ws, size_t ws_size,
                              hipStream_t stream)
{
  const float* x   = (const float*)d_in[0];
  const float* Wih = (const float*)d_in[1];
  const float* Whh = (const float*)d_in[2];
  const float* bih = (const float*)d_in[3];
  const float* bhh = (const float*)d_in[4];
  float* out = (float*)d_out;

  // ws layout (72 MB total):
  float*  xg  = (float*)d_ws;                              // 32 MB
  float*  cst = xg + (size_t)B_SZ * G_SZ;                  //  8 MB
  bf16x8* Wh  = (bf16x8*)(cst + (size_t)B_SZ * H_SZ);      //  8 MB
  bf16x8* Wl  = Wh + 524288;                               //  8 MB
  bf16x8* hAh = Wl + 524288;                               //  4 MB
  bf16x8* hAl = hAh + 262144;                              //  4 MB
  bf16x8* hBh = hAl + 262144;                              //  4 MB
  bf16x8* hBl = hBh + 262144;                              //  4 MB

  repack_whh<<<2048, 256, 0, stream>>>(Whh, Wh, Wl);
  init_h0<<<1024, 256, 0, stream>>>(hAh, hAl);
  xg_gemm<<<dim3(G_SZ / 128, B_SZ / 128), 256, 0, stream>>>(x, Wih, bih, bhh, xg);

  for (int t = 0; t < T_STEPS; ++t) {
    const bf16x8* rh = (t & 1) ? hBh : hAh;
    const bf16x8* rl = (t & 1) ? hBl : hAl;
    bf16x8* wh = (t & 1) ? hAh : hBh;
    bf16x8* wl = (t & 1) ? hAl : hBl;
    lstm_step<<<256, 512, 0, stream>>>(rh, rl, Wh, Wl, xg, cst,
                                       out + (size_t)t * B_SZ * H_SZ, wh, wl,
                                       t == 0 ? 1 : 0);
  }
}

// Round 6
// 882.098 us; speedup vs baseline: 1.5199x; 1.1847x over previous
//
#include <hip/hip_runtime.h>
#include <hip/hip_bf16.h>

typedef float f32x4 __attribute__((ext_vector_type(4)));
typedef __bf16 bf16x8 __attribute__((ext_vector_type(8)));

#define B_SZ 2048
#define IN_SZ 2048
#define H_SZ 1024
#define G_SZ (4 * H_SZ)   // 4096
#define T_STEPS 15
#define INIT_ST 0.01f

__device__ __forceinline__ float sigmoid_f(float x) { return 1.0f / (1.0f + __expf(-x)); }
__device__ __forceinline__ float tanh_f(float x)    { return 1.0f - 2.0f / (__expf(2.0f * x) + 1.0f); }

// fp32x8 -> bf16 hi + bf16 lo (Markidis split)
__device__ __forceinline__ void split8(f32x4 v0, f32x4 v1, bf16x8* h, bf16x8* l) {
  bf16x8 hv, lv;
  #pragma unroll
  for (int j = 0; j < 4; ++j) {
    float f = v0[j];
    __bf16 hb = (__bf16)f;
    hv[j] = hb;
    lv[j] = (__bf16)(f - (float)hb);
  }
  #pragma unroll
  for (int j = 0; j < 4; ++j) {
    float f = v1[j];
    __bf16 hb = (__bf16)f;
    hv[4 + j] = hb;
    lv[4 + j] = (__bf16)(f - (float)hb);
  }
  *h = hv;
  *l = lv;
}

// fp32x8 -> bf16 (round-to-nearest, hi only)
__device__ __forceinline__ bf16x8 cvt8(f32x4 v0, f32x4 v1) {
  bf16x8 hv;
  #pragma unroll
  for (int j = 0; j < 4; ++j) hv[j] = (__bf16)v0[j];
  #pragma unroll
  for (int j = 0; j < 4; ++j) hv[4 + j] = (__bf16)v1[j];
  return hv;
}

// async global -> LDS, 16 bytes/lane; src per-lane, dest wave-uniform base.
__device__ __forceinline__ void gl16(const bf16x8* src, bf16x8* lds_base_uniform) {
  __builtin_amdgcn_global_load_lds(
      (const __attribute__((address_space(1))) void*)src,
      (__attribute__((address_space(3))) void*)lds_base_uniform, 16, 0, 0);
}

// ---------------------------------------------------------------------------
// Repack W_hh (fp32 [4096][1024]) -> bf16 (hi only) chunks in B-tile order:
//   cid = ((nt*32 + ks)*1024 + s);  s: row = s>>2 (0..255), kc = (s&3)^(row&3)
//   row: gate = row>>6, col = row&63
// 2-term split: recurrence uses full-precision h x bf16(W) == ah*bh + al*bh.
// ---------------------------------------------------------------------------
__global__ __launch_bounds__(256)
void repack_whh(const float* __restrict__ Whh, bf16x8* __restrict__ Wh)
{
  int cid = blockIdx.x * 256 + threadIdx.x;     // 0 .. 524287
  int s    = cid & 1023;
  int rest = cid >> 10;       // nt*32 + ks
  int ks   = rest & 31;
  int nt   = rest >> 5;       // 0..15
  int row  = s >> 2;          // 0..255
  int kc   = (s & 3) ^ (row & 3);
  int gate = row >> 6, col = row & 63;
  const float* src = Whh + (size_t)(gate * H_SZ + nt * 64 + col) * H_SZ + ks * 32 + kc * 8;
  Wh[cid] = cvt8(*(const f32x4*)src, *(const f32x4*)(src + 4));
}

// h0 = 0.01 everywhere, pre-split (layout-independent since constant)
__global__ __launch_bounds__(256)
void init_h0(bf16x8* __restrict__ hh, bf16x8* __restrict__ hl)
{
  int cid = blockIdx.x * 256 + threadIdx.x;     // 0 .. 262143
  __bf16 hi = (__bf16)INIT_ST;
  __bf16 lo = (__bf16)(INIT_ST - (float)hi);
  bf16x8 h, l;
  #pragma unroll
  for (int j = 0; j < 8; ++j) { h[j] = hi; l[j] = lo; }
  hh[cid] = h;
  hl[cid] = l;
}

// ---------------------------------------------------------------------------
// xg = x @ W_ih^T + b_ih + b_hh   (3-term split; unchanged — control)
// ---------------------------------------------------------------------------
__global__ __launch_bounds__(256, 2)
void xg_gemm(const float* __restrict__ x, const float* __restrict__ Wih,
             const float* __restrict__ bih, const float* __restrict__ bhh,
             float* __restrict__ xg)
{
  __shared__ bf16x8 Ah[128 * 4], Al[128 * 4], Bh[128 * 4], Bl[128 * 4];
  const int tid  = threadIdx.x;
  const int lane = tid & 63;
  const int wv   = tid >> 6;
  const int wm   = wv >> 1, wn = wv & 1;
  const int bm   = blockIdx.y * 128;
  const int bn   = blockIdx.x * 128;

  f32x4 acc[4][4] = {};

  for (int k0 = 0; k0 < IN_SZ; k0 += 32) {
    #pragma unroll
    for (int c = 0; c < 2; ++c) {
      int cid = tid + c * 256;
      int row = cid >> 2, kc = cid & 3;
      int idx = row * 4 + (kc ^ (row & 3));
      const float* srcA = x + (size_t)(bm + row) * IN_SZ + k0 + kc * 8;
      split8(*(const f32x4*)srcA, *(const f32x4*)(srcA + 4), &Ah[idx], &Al[idx]);
      const float* srcB = Wih + (size_t)(bn + row) * IN_SZ + k0 + kc * 8;
      split8(*(const f32x4*)srcB, *(const f32x4*)(srcB + 4), &Bh[idx], &Bl[idx]);
    }
    __syncthreads();

    const int kc = lane >> 4;
    bf16x8 ah[4], al[4], bh[4], bl[4];
    #pragma unroll
    for (int i = 0; i < 4; ++i) {
      int ra = wm * 64 + i * 16 + (lane & 15);
      int ia = ra * 4 + (kc ^ (ra & 3));
      ah[i] = Ah[ia]; al[i] = Al[ia];
      int rb = wn * 64 + i * 16 + (lane & 15);
      int ib = rb * 4 + (kc ^ (rb & 3));
      bh[i] = Bh[ib]; bl[i] = Bl[ib];
    }
    #pragma unroll
    for (int i = 0; i < 4; ++i)
      #pragma unroll
      for (int j = 0; j < 4; ++j) {
        acc[i][j] = __builtin_amdgcn_mfma_f32_16x16x32_bf16(ah[i], bh[j], acc[i][j], 0, 0, 0);
        acc[i][j] = __builtin_amdgcn_mfma_f32_16x16x32_bf16(ah[i], bl[j], acc[i][j], 0, 0, 0);
        acc[i][j] = __builtin_amdgcn_mfma_f32_16x16x32_bf16(al[i], bh[j], acc[i][j], 0, 0, 0);
      }
    __syncthreads();
  }

  #pragma unroll
  for (int i = 0; i < 4; ++i) {
    int m0 = bm + wm * 64 + i * 16 + ((lane >> 4) * 4);
    #pragma unroll
    for (int j = 0; j < 4; ++j) {
      int n = bn + wn * 64 + j * 16 + (lane & 15);
      float bb = bih[n] + bhh[n];
      #pragma unroll
      for (int r = 0; r < 4; ++r)
        xg[(size_t)(m0 + r) * G_SZ + n] = acc[i][j][r] + bb;
    }
  }
}

// ---------------------------------------------------------------------------
// Fused LSTM step, 2-term split (full h x bf16 W):
//   BM=128 batch x (4 gates x 64 cols), BK=32, 512 threads = 8 waves
//   Triple-buffered LDS (3 x 32 KB = 96 KB), counted vmcnt(4), 1 barrier/K-step
//   32 MFMA / K-step / wave.
// ---------------------------------------------------------------------------
__global__ __launch_bounds__(512, 2)
void lstm_step(const bf16x8* __restrict__ hsh,  // h_prev split hi (A-layout)
               const bf16x8* __restrict__ hsl,  // h_prev split lo
               const bf16x8* __restrict__ Wh,   // W_hh bf16 (repacked)
               const float* __restrict__ xg,    // [2048][4096], biases folded
               float* __restrict__ cst,         // [2048][1024]
               float* __restrict__ hout,        // fp32 out slice
               bf16x8* __restrict__ hnh,        // next-step h split hi
               bf16x8* __restrict__ hnl,        // next-step h split lo
               int first)
{
  __shared__ __attribute__((aligned(16))) char smem[98304];
  bf16x8* AhL = (bf16x8*)smem;            // [3][512]
  bf16x8* AlL = AhL + 3 * 512;            // [3][512]
  bf16x8* BhL = AlL + 3 * 512;            // [3][1024]

  const int tid  = threadIdx.x;
  const int lane = tid & 63;
  const int wv   = tid >> 6;
  const int wm   = wv >> 2;        // batch half 0..1
  const int wg   = wv & 3;         // gate 0..3

  // XCD-aware remap: 256 blocks, 32/XCD.
  const int bid  = blockIdx.x;
  const int wgid = (bid & 7) * 32 + (bid >> 3);
  const int nt   = wgid >> 4;      // 0..15 hidden-col tile
  const int mt   = wgid & 15;      // 0..15 batch tile (128 rows)

  f32x4 acc[4][4] = {};
  const size_t abase = (size_t)mt * 32;
  const size_t bbase = (size_t)nt * 32;
  const int kc = lane >> 4;

#define STAGE(BUF, KS)                                                      \
  do {                                                                      \
    const bf16x8* sa_h = hsh + (abase + (KS)) * 512 + wv * 64 + lane;       \
    const bf16x8* sa_l = hsl + (abase + (KS)) * 512 + wv * 64 + lane;       \
    gl16(sa_h, AhL + (BUF) * 512 + wv * 64);                                \
    gl16(sa_l, AlL + (BUF) * 512 + wv * 64);                                \
    const bf16x8* sb_h = Wh + (bbase + (KS)) * 1024 + wv * 128;             \
    gl16(sb_h + lane,      BhL + (BUF) * 1024 + wv * 128);                  \
    gl16(sb_h + 64 + lane, BhL + (BUF) * 1024 + wv * 128 + 64);             \
  } while (0)

#define COMPUTE(BUF)                                                        \
  do {                                                                      \
    bf16x8 ah[4], al[4], bh[4];                                             \
    _Pragma("unroll")                                                       \
    for (int i = 0; i < 4; ++i) {                                           \
      int ra = wm * 64 + i * 16 + (lane & 15);                              \
      int ia = (BUF) * 512 + ra * 4 + (kc ^ (ra & 3));                      \
      ah[i] = AhL[ia]; al[i] = AlL[ia];                                     \
      int rb = wg * 64 + i * 16 + (lane & 15);                              \
      int ib = (BUF) * 1024 + rb * 4 + (kc ^ (rb & 3));                     \
      bh[i] = BhL[ib];                                                      \
    }                                                                       \
    __builtin_amdgcn_s_setprio(1);                                          \
    _Pragma("unroll")                                                       \
    for (int i = 0; i < 4; ++i)                                             \
      _Pragma("unroll")                                                     \
      for (int j = 0; j < 4; ++j) {                                         \
        acc[i][j] = __builtin_amdgcn_mfma_f32_16x16x32_bf16(ah[i], bh[j], acc[i][j], 0, 0, 0); \
        acc[i][j] = __builtin_amdgcn_mfma_f32_16x16x32_bf16(al[i], bh[j], acc[i][j], 0, 0, 0); \
      }                                                                     \
    __builtin_amdgcn_s_setprio(0);                                          \
  } while (0)

// one K-step: wait cur loads landed (4 newest still in flight), sync,
// issue stage 2-ahead, compute cur
#define KSTEP(CUR, TGT, KST)                                                \
  do {                                                                      \
    asm volatile("s_waitcnt vmcnt(4)" ::: "memory");                        \
    __builtin_amdgcn_s_barrier();                                           \
    STAGE(TGT, KST);                                                        \
    COMPUTE(CUR);                                                           \
  } while (0)

  STAGE(0, 0);
  STAGE(1, 1);

  int ks = 0;
  #pragma unroll 1
  for (int blk = 0; blk < 10; ++blk) {
    KSTEP(0, 2, ks + 2);
    KSTEP(1, 0, ks + 3);
    KSTEP(2, 1, ks + 4);
    ks += 3;
  }
  // ks = 30, 31 peeled (no more staging)
  asm volatile("s_waitcnt vmcnt(4)" ::: "memory");
  __builtin_amdgcn_s_barrier();
  COMPUTE(0);
  asm volatile("s_waitcnt vmcnt(0)" ::: "memory");
  __builtin_amdgcn_s_barrier();
  COMPUTE(1);
  __builtin_amdgcn_s_barrier();    // all reads done -> smem reusable

#undef KSTEP
#undef COMPUTE
#undef STAGE

  // ------------------------- fused epilogue --------------------------------
  const int bm = mt * 128, bn = nt * 64;
  const int nl = (tid & 15) * 4;      // 4 n-cols per thread
  const int ml = (tid >> 4) * 4;      // 4 m-rows per thread

  // prefetch xg (4 gates) and c for this thread's 4x4 block
  f32x4 xgv[4][4], cv[4];
  #pragma unroll
  for (int r = 0; r < 4; ++r) {
    int m = bm + ml + r;
    const float* xr = xg + (size_t)m * G_SZ + bn + nl;
    #pragma unroll
    for (int g = 0; g < 4; ++g) xgv[g][r] = *(const f32x4*)(xr + g * H_SZ);
    if (first) cv[r] = (f32x4){INIT_ST, INIT_ST, INIT_ST, INIT_ST};
    else       cv[r] = *(const f32x4*)(cst + (size_t)m * H_SZ + bn + nl);
  }

  float* pre = (float*)smem;          // [2][128][68] fp32, +4 pad (69632 B)

  // phase 1: gates 0 (i), 1 (f)
  if (wg < 2) {
    #pragma unroll
    for (int i = 0; i < 4; ++i)
      #pragma unroll
      for (int j = 0; j < 4; ++j) {
        int n = j * 16 + (lane & 15);
        #pragma unroll
        for (int r = 0; r < 4; ++r) {
          int m = wm * 64 + i * 16 + ((lane >> 4) * 4) + r;
          pre[(wg * 128 + m) * 68 + n] = acc[i][j][r];
        }
      }
  }
  asm volatile("s_waitcnt lgkmcnt(0)" ::: "memory");
  __builtin_amdgcn_s_barrier();

  f32x4 iv[4], fv[4];
  #pragma unroll
  for (int r = 0; r < 4; ++r) {
    int m = ml + r;
    f32x4 pi = *(const f32x4*)&pre[(0 * 128 + m) * 68 + nl];
    f32x4 pf = *(const f32x4*)&pre[(1 * 128 + m) * 68 + nl];
    #pragma unroll
    for (int j = 0; j < 4; ++j) {
      iv[r][j] = sigmoid_f(pi[j] + xgv[0][r][j]);
      fv[r][j] = sigmoid_f(pf[j] + xgv[1][r][j]);
    }
  }
  __builtin_amdgcn_s_barrier();       // phase-1 reads done before overwrite

  // phase 2: gates 2 (g), 3 (o)
  if (wg >= 2) {
    #pragma unroll
    for (int i = 0; i < 4; ++i)
      #pragma unroll
      for (int j = 0; j < 4; ++j) {
        int n = j * 16 + (lane & 15);
        #pragma unroll
        for (int r = 0; r < 4; ++r) {
          int m = wm * 64 + i * 16 + ((lane >> 4) * 4) + r;
          pre[((wg - 2) * 128 + m) * 68 + n] = acc[i][j][r];
        }
      }
  }
  asm volatile("s_waitcnt lgkmcnt(0)" ::: "memory");
  __builtin_amdgcn_s_barrier();

  __bf16* ph = (__bf16*)hnh;
  __bf16* pl = (__bf16*)hnl;
  #pragma unroll
  for (int r = 0; r < 4; ++r) {
    int m = ml + r;
    f32x4 pg = *(const f32x4*)&pre[(0 * 128 + m) * 68 + nl];
    f32x4 po = *(const f32x4*)&pre[(1 * 128 + m) * 68 + nl];
    f32x4 cnew, hv;
    #pragma unroll
    for (int j = 0; j < 4; ++j) {
      float gv = tanh_f(pg[j] + xgv[2][r][j]);
      float ov = sigmoid_f(po[j] + xgv[3][r][j]);
      cnew[j] = fv[r][j] * cv[r][j] + iv[r][j] * gv;
      hv[j]   = ov * tanh_f(cnew[j]);
    }
    int mg = bm + m;
    *(f32x4*)(cst  + (size_t)mg * H_SZ + bn + nl) = cnew;
    *(f32x4*)(hout + (size_t)mg * H_SZ + bn + nl) = hv;

    // split for next step's A layout (128-row tiles)
    int nglob = bn + nl;
    int ks2 = nglob >> 5;
    int kc2 = (nglob >> 3) & 3;
    int eb  = nglob & 7;                 // 0 or 4
    int s2  = m * 4 + (kc2 ^ (m & 3));
    size_t ci = (((size_t)mt * 32 + ks2) * 512 + s2) * 8 + eb;
    union { __bf16 b[4]; uint2 u; } uh, ul;
    #pragma unroll
    for (int j = 0; j < 4; ++j) {
      __bf16 hb = (__bf16)hv[j];
      uh.b[j] = hb;
      ul.b[j] = (__bf16)(hv[j] - (float)hb);
    }
    *(uint2*)(ph + ci) = uh.u;
    *(uint2*)(pl + ci) = ul.u;
  }
}

extern "C" void kernel_launch(void* const* d_in, const int* in_sizes, int n_in,
                              void* d_out, int out_size, void* d_ws, size_t ws_size,
                              hipStream_t stream)
{
  const float* x   = (const float*)d_in[0];
  const float* Wih = (const float*)d_in[1];
  const float* Whh = (const float*)d_in[2];
  const float* bih = (const float*)d_in[3];
  const float* bhh = (const float*)d_in[4];
  float* out = (float*)d_out;

  // ws layout (64 MB total):
  float*  xg  = (float*)d_ws;                              // 32 MB
  float*  cst = xg + (size_t)B_SZ * G_SZ;                  //  8 MB
  bf16x8* Wh  = (bf16x8*)(cst + (size_t)B_SZ * H_SZ);      //  8 MB
  bf16x8* hAh = Wh + 524288;                               //  4 MB
  bf16x8* hAl = hAh + 262144;                              //  4 MB
  bf16x8* hBh = hAl + 262144;                              //  4 MB
  bf16x8* hBl = hBh + 262144;                              //  4 MB

  repack_whh<<<2048, 256, 0, stream>>>(Whh, Wh);
  init_h0<<<1024, 256, 0, stream>>>(hAh, hAl);
  xg_gemm<<<dim3(G_SZ / 128, B_SZ / 128), 256, 0, stream>>>(x, Wih, bih, bhh, xg);

  for (int t = 0; t < T_STEPS; ++t) {
    const bf16x8* rh = (t & 1) ? hBh : hAh;
    const bf16x8* rl = (t & 1) ? hBl : hAl;
    bf16x8* wh = (t & 1) ? hAh : hBh;
    bf16x8* wl = (t & 1) ? hAl : hBl;
    lstm_step<<<256, 512, 0, stream>>>(rh, rl, Wh, xg, cst,
                                       out + (size_t)t * B_SZ * H_SZ, wh, wl,
                                       t == 0 ? 1 : 0);
  }
}

// Round 7
// 869.444 us; speedup vs baseline: 1.5421x; 1.0146x over previous
//
#include <hip/hip_runtime.h>
#include <hip/hip_bf16.h>

typedef float f32x4 __attribute__((ext_vector_type(4)));
typedef __bf16 bf16x8 __attribute__((ext_vector_type(8)));

#define B_SZ 2048
#define IN_SZ 2048
#define H_SZ 1024
#define G_SZ (4 * H_SZ)   // 4096
#define T_STEPS 15
#define INIT_ST 0.01f

__device__ __forceinline__ float sigmoid_f(float x) { return 1.0f / (1.0f + __expf(-x)); }
__device__ __forceinline__ float tanh_f(float x)    { return 1.0f - 2.0f / (__expf(2.0f * x) + 1.0f); }

// fp32x8 -> bf16 hi + bf16 lo (Markidis split)
__device__ __forceinline__ void split8(f32x4 v0, f32x4 v1, bf16x8* h, bf16x8* l) {
  bf16x8 hv, lv;
  #pragma unroll
  for (int j = 0; j < 4; ++j) {
    float f = v0[j];
    __bf16 hb = (__bf16)f;
    hv[j] = hb;
    lv[j] = (__bf16)(f - (float)hb);
  }
  #pragma unroll
  for (int j = 0; j < 4; ++j) {
    float f = v1[j];
    __bf16 hb = (__bf16)f;
    hv[4 + j] = hb;
    lv[4 + j] = (__bf16)(f - (float)hb);
  }
  *h = hv;
  *l = lv;
}

// fp32x8 -> bf16 (round-to-nearest, hi only)
__device__ __forceinline__ bf16x8 cvt8(f32x4 v0, f32x4 v1) {
  bf16x8 hv;
  #pragma unroll
  for (int j = 0; j < 4; ++j) hv[j] = (__bf16)v0[j];
  #pragma unroll
  for (int j = 0; j < 4; ++j) hv[4 + j] = (__bf16)v1[j];
  return hv;
}

// async global -> LDS, 16 bytes/lane; src per-lane, dest wave-uniform base.
__device__ __forceinline__ void gl16(const bf16x8* src, bf16x8* lds_base_uniform) {
  __builtin_amdgcn_global_load_lds(
      (const __attribute__((address_space(1))) void*)src,
      (__attribute__((address_space(3))) void*)lds_base_uniform, 16, 0, 0);
}

// ---------------------------------------------------------------------------
// Repack W_hh (fp32 [4096][1024]) -> bf16 chunks in B-tile order (unchanged):
//   cid = ((nt*32 + ks)*1024 + s);  s: row = s>>2 (0..255), kc = (s&3)^(row&3)
//   row: gate = row>>6, col = row&63
// ---------------------------------------------------------------------------
__global__ __launch_bounds__(256)
void repack_whh(const float* __restrict__ Whh, bf16x8* __restrict__ Wh)
{
  int cid = blockIdx.x * 256 + threadIdx.x;     // 0 .. 524287
  int s    = cid & 1023;
  int rest = cid >> 10;       // nt*32 + ks
  int ks   = rest & 31;
  int nt   = rest >> 5;       // 0..15
  int row  = s >> 2;          // 0..255
  int kc   = (s & 3) ^ (row & 3);
  int gate = row >> 6, col = row & 63;
  const float* src = Whh + (size_t)(gate * H_SZ + nt * 64 + col) * H_SZ + ks * 32 + kc * 8;
  Wh[cid] = cvt8(*(const f32x4*)src, *(const f32x4*)(src + 4));
}

// h0 = 0.01 everywhere, pre-split (layout-independent since constant)
__global__ __launch_bounds__(256)
void init_h0(bf16x8* __restrict__ hh, bf16x8* __restrict__ hl)
{
  int cid = blockIdx.x * 256 + threadIdx.x;     // 0 .. 262143
  __bf16 hi = (__bf16)INIT_ST;
  __bf16 lo = (__bf16)(INIT_ST - (float)hi);
  bf16x8 h, l;
  #pragma unroll
  for (int j = 0; j < 8; ++j) { h[j] = hi; l[j] = lo; }
  hh[cid] = h;
  hl[cid] = l;
}

// ---------------------------------------------------------------------------
// xg = x @ W_ih^T + b_ih + b_hh   (3-term split; unchanged — control)
// ---------------------------------------------------------------------------
__global__ __launch_bounds__(256, 2)
void xg_gemm(const float* __restrict__ x, const float* __restrict__ Wih,
             const float* __restrict__ bih, const float* __restrict__ bhh,
             float* __restrict__ xg)
{
  __shared__ bf16x8 Ah[128 * 4], Al[128 * 4], Bh[128 * 4], Bl[128 * 4];
  const int tid  = threadIdx.x;
  const int lane = tid & 63;
  const int wv   = tid >> 6;
  const int wm   = wv >> 1, wn = wv & 1;
  const int bm   = blockIdx.y * 128;
  const int bn   = blockIdx.x * 128;

  f32x4 acc[4][4] = {};

  for (int k0 = 0; k0 < IN_SZ; k0 += 32) {
    #pragma unroll
    for (int c = 0; c < 2; ++c) {
      int cid = tid + c * 256;
      int row = cid >> 2, kc = cid & 3;
      int idx = row * 4 + (kc ^ (row & 3));
      const float* srcA = x + (size_t)(bm + row) * IN_SZ + k0 + kc * 8;
      split8(*(const f32x4*)srcA, *(const f32x4*)(srcA + 4), &Ah[idx], &Al[idx]);
      const float* srcB = Wih + (size_t)(bn + row) * IN_SZ + k0 + kc * 8;
      split8(*(const f32x4*)srcB, *(const f32x4*)(srcB + 4), &Bh[idx], &Bl[idx]);
    }
    __syncthreads();

    const int kc = lane >> 4;
    bf16x8 ah[4], al[4], bh[4], bl[4];
    #pragma unroll
    for (int i = 0; i < 4; ++i) {
      int ra = wm * 64 + i * 16 + (lane & 15);
      int ia = ra * 4 + (kc ^ (ra & 3));
      ah[i] = Ah[ia]; al[i] = Al[ia];
      int rb = wn * 64 + i * 16 + (lane & 15);
      int ib = rb * 4 + (kc ^ (rb & 3));
      bh[i] = Bh[ib]; bl[i] = Bl[ib];
    }
    #pragma unroll
    for (int i = 0; i < 4; ++i)
      #pragma unroll
      for (int j = 0; j < 4; ++j) {
        acc[i][j] = __builtin_amdgcn_mfma_f32_16x16x32_bf16(ah[i], bh[j], acc[i][j], 0, 0, 0);
        acc[i][j] = __builtin_amdgcn_mfma_f32_16x16x32_bf16(ah[i], bl[j], acc[i][j], 0, 0, 0);
        acc[i][j] = __builtin_amdgcn_mfma_f32_16x16x32_bf16(al[i], bh[j], acc[i][j], 0, 0, 0);
      }
    __syncthreads();
  }

  #pragma unroll
  for (int i = 0; i < 4; ++i) {
    int m0 = bm + wm * 64 + i * 16 + ((lane >> 4) * 4);
    #pragma unroll
    for (int j = 0; j < 4; ++j) {
      int n = bn + wn * 64 + j * 16 + (lane & 15);
      float bb = bih[n] + bhh[n];
      #pragma unroll
      for (int r = 0; r < 4; ++r)
        xg[(size_t)(m0 + r) * G_SZ + n] = acc[i][j][r] + bb;
    }
  }
}

// ---------------------------------------------------------------------------
// Fused LSTM step v3:
//   BM=64 batch x (4 gates x 64 cols), BK=32, 256 threads = 4 waves (1/gate)
//   Ring-3 LDS (3 x 24 KB = 72 KB) -> 2 blocks/CU (cross-block overlap)
//   Register frag double-buffer: read frags[ks+1] under MFMA[ks]
//   Stage 3 ahead, vmcnt(6) (never 0 in loop); lgkmcnt(0) before each barrier
//   guards LDS WAR. Math order identical to round 6 -> bit-identical output.
// ---------------------------------------------------------------------------
__global__ __launch_bounds__(256, 2)
void lstm_step(const bf16x8* __restrict__ hsh,  // h_prev split hi [32mt][32ks][256]
               const bf16x8* __restrict__ hsl,  // h_prev split lo
               const bf16x8* __restrict__ Wh,   // W_hh bf16 [16nt][32ks][1024]
               const float* __restrict__ xg,    // [2048][4096], biases folded
               float* __restrict__ cst,         // [2048][1024]
               float* __restrict__ hout,        // fp32 out slice
               bf16x8* __restrict__ hnh,        // next-step h split hi
               bf16x8* __restrict__ hnl,        // next-step h split lo
               int first)
{
  __shared__ __attribute__((aligned(16))) char smem[73728];  // 3 x 24 KB
  bf16x8* L = (bf16x8*)smem;   // per buf (1536 units): [A hi 256][A lo 256][B 1024]

  const int tid  = threadIdx.x;
  const int lane = tid & 63;
  const int wv   = tid >> 6;       // wave 0..3
  const int wg   = wv;             // gate = wave

  // XCD-aware remap: 512 blocks, 64/XCD -> each XCD owns 2 nt slices.
  const int bid  = blockIdx.x;
  const int wgid = (bid & 7) * 64 + (bid >> 3);
  const int nt   = wgid >> 5;      // 0..15 hidden-col tile
  const int mt   = wgid & 31;      // 0..31 batch tile (64 rows)

  f32x4 acc[4][4] = {};
  const size_t abase = (size_t)mt * 32;
  const size_t bbase = (size_t)nt * 32;
  const int kc = lane >> 4;

  bf16x8 ahA[4], alA[4], bhA[4];   // frag set A (even ks)
  bf16x8 ahB[4], alB[4], bhB[4];   // frag set B (odd ks)

#define STAGE(BUF, KS)                                                      \
  do {                                                                      \
    gl16(hsh + (abase + (KS)) * 256 + tid, L + (BUF) * 1536 + wv * 64);     \
    gl16(hsl + (abase + (KS)) * 256 + tid, L + (BUF) * 1536 + 256 + wv * 64); \
    const bf16x8* sb = Wh + (bbase + (KS)) * 1024;                          \
    gl16(sb + tid,       L + (BUF) * 1536 + 512 + wv * 64);                 \
    gl16(sb + 256 + tid, L + (BUF) * 1536 + 768 + wv * 64);                 \
    gl16(sb + 512 + tid, L + (BUF) * 1536 + 1024 + wv * 64);                \
    gl16(sb + 768 + tid, L + (BUF) * 1536 + 1280 + wv * 64);                \
  } while (0)

#define READF(S, BUF)                                                       \
  do {                                                                      \
    _Pragma("unroll")                                                       \
    for (int i = 0; i < 4; ++i) {                                           \
      int ra = i * 16 + (lane & 15);                                        \
      int ca = (BUF) * 1536 + ra * 4 + (kc ^ (ra & 3));                     \
      ah##S[i] = L[ca];                                                     \
      al##S[i] = L[ca + 256];                                               \
      int rb = wg * 64 + i * 16 + (lane & 15);                              \
      int cb = (BUF) * 1536 + 512 + rb * 4 + (kc ^ (rb & 3));               \
      bh##S[i] = L[cb];                                                     \
    }                                                                       \
  } while (0)

#define MFMAF(S)                                                            \
  do {                                                                      \
    __builtin_amdgcn_s_setprio(1);                                          \
    _Pragma("unroll")                                                       \
    for (int i = 0; i < 4; ++i)                                             \
      _Pragma("unroll")                                                     \
      for (int j = 0; j < 4; ++j) {                                         \
        acc[i][j] = __builtin_amdgcn_mfma_f32_16x16x32_bf16(ah##S[i], bh##S[j], acc[i][j], 0, 0, 0); \
        acc[i][j] = __builtin_amdgcn_mfma_f32_16x16x32_bf16(al##S[i], bh##S[j], acc[i][j], 0, 0, 0); \
      }                                                                     \
    __builtin_amdgcn_s_setprio(0);                                          \
  } while (0)

// iter ks: drain own prev reads (WAR guard), ensure tile ks+1 landed (newest
// 6 outstanding = tile ks+2's stage), sync, stage ks+3 into buf ks%3 (just
// finished being read), read frags[ks+1], MFMA frags[ks].
#define ITER(KS, SB, RB, RS, MS)                                            \
  do {                                                                      \
    asm volatile("s_waitcnt lgkmcnt(0)" ::: "memory");                      \
    asm volatile("s_waitcnt vmcnt(6)" ::: "memory");                        \
    __builtin_amdgcn_s_barrier();                                           \
    STAGE(SB, (KS) + 3);                                                    \
    READF(RS, RB);                                                          \
    MFMAF(MS);                                                              \
  } while (0)

  STAGE(0, 0);
  STAGE(1, 1);
  STAGE(2, 2);                          // 18 loads in flight
  asm volatile("s_waitcnt vmcnt(12)" ::: "memory");   // tile 0 landed
  __builtin_amdgcn_s_barrier();
  READF(A, 0);                          // frags for ks=0

  #pragma unroll 1
  for (int r6 = 0; r6 < 24; r6 += 6) {
    ITER(r6 + 0, 0, 1, B, A);
    ITER(r6 + 1, 1, 2, A, B);
    ITER(r6 + 2, 2, 0, B, A);
    ITER(r6 + 3, 0, 1, A, B);
    ITER(r6 + 4, 1, 2, B, A);
    ITER(r6 + 5, 2, 0, A, B);
  }
  ITER(24, 0, 1, B, A);
  ITER(25, 1, 2, A, B);
  ITER(26, 2, 0, B, A);
  ITER(27, 0, 1, A, B);                 // stages tile 30 -> buf 0
  ITER(28, 1, 2, B, A);                 // stages tile 31 -> buf 1
  // ks = 29: tiles 30,31 in flight; vmcnt(6) -> 30 landed
  asm volatile("s_waitcnt lgkmcnt(0)" ::: "memory");
  asm volatile("s_waitcnt vmcnt(6)" ::: "memory");
  __builtin_amdgcn_s_barrier();
  READF(A, 0);                          // frags for 30 (buf 30%3 = 0)
  MFMAF(B);                             // ks=29
  // ks = 30: need tile 31 -> vmcnt(0) (epilogue next anyway)
  asm volatile("s_waitcnt lgkmcnt(0)" ::: "memory");
  asm volatile("s_waitcnt vmcnt(0)" ::: "memory");
  __builtin_amdgcn_s_barrier();
  READF(B, 1);                          // frags for 31 (buf 31%3 = 1)
  MFMAF(A);                             // ks=30
  MFMAF(B);                             // ks=31
  __builtin_amdgcn_s_barrier();         // all LDS reads done -> smem reusable

#undef ITER
#undef MFMAF
#undef READF
#undef STAGE

  // ------------------------- fused epilogue --------------------------------
  const int bm = mt * 64, bn = nt * 64;
  const int nl = (tid & 15) * 4;      // 4 n-cols per thread
  const int ml = (tid >> 4) * 4;      // 4 m-rows per thread

  // prefetch xg (4 gates) and c for this thread's 4x4 block
  f32x4 xgv[4][4], cv[4];
  #pragma unroll
  for (int r = 0; r < 4; ++r) {
    int m = bm + ml + r;
    const float* xr = xg + (size_t)m * G_SZ + bn + nl;
    #pragma unroll
    for (int g = 0; g < 4; ++g) xgv[g][r] = *(const f32x4*)(xr + g * H_SZ);
    if (first) cv[r] = (f32x4){INIT_ST, INIT_ST, INIT_ST, INIT_ST};
    else       cv[r] = *(const f32x4*)(cst + (size_t)m * H_SZ + bn + nl);
  }

  float* pre = (float*)smem;          // [2][64][68] fp32 = 34816 B

  // phase 1: gates 0 (i), 1 (f)
  if (wg < 2) {
    #pragma unroll
    for (int i = 0; i < 4; ++i)
      #pragma unroll
      for (int j = 0; j < 4; ++j) {
        int n = j * 16 + (lane & 15);
        #pragma unroll
        for (int r = 0; r < 4; ++r) {
          int m = i * 16 + ((lane >> 4) * 4) + r;
          pre[(wg * 64 + m) * 68 + n] = acc[i][j][r];
        }
      }
  }
  asm volatile("s_waitcnt lgkmcnt(0)" ::: "memory");
  __builtin_amdgcn_s_barrier();

  f32x4 iv[4], fv[4];
  #pragma unroll
  for (int r = 0; r < 4; ++r) {
    int m = ml + r;
    f32x4 pi = *(const f32x4*)&pre[(0 * 64 + m) * 68 + nl];
    f32x4 pf = *(const f32x4*)&pre[(1 * 64 + m) * 68 + nl];
    #pragma unroll
    for (int j = 0; j < 4; ++j) {
      iv[r][j] = sigmoid_f(pi[j] + xgv[0][r][j]);
      fv[r][j] = sigmoid_f(pf[j] + xgv[1][r][j]);
    }
  }
  __builtin_amdgcn_s_barrier();       // phase-1 reads done before overwrite

  // phase 2: gates 2 (g), 3 (o)
  if (wg >= 2) {
    #pragma unroll
    for (int i = 0; i < 4; ++i)
      #pragma unroll
      for (int j = 0; j < 4; ++j) {
        int n = j * 16 + (lane & 15);
        #pragma unroll
        for (int r = 0; r < 4; ++r) {
          int m = i * 16 + ((lane >> 4) * 4) + r;
          pre[((wg - 2) * 64 + m) * 68 + n] = acc[i][j][r];
        }
      }
  }
  asm volatile("s_waitcnt lgkmcnt(0)" ::: "memory");
  __builtin_amdgcn_s_barrier();

  __bf16* ph = (__bf16*)hnh;
  __bf16* pl = (__bf16*)hnl;
  #pragma unroll
  for (int r = 0; r < 4; ++r) {
    int m = ml + r;
    f32x4 pg = *(const f32x4*)&pre[(0 * 64 + m) * 68 + nl];
    f32x4 po = *(const f32x4*)&pre[(1 * 64 + m) * 68 + nl];
    f32x4 cnew, hv;
    #pragma unroll
    for (int j = 0; j < 4; ++j) {
      float gv = tanh_f(pg[j] + xgv[2][r][j]);
      float ov = sigmoid_f(po[j] + xgv[3][r][j]);
      cnew[j] = fv[r][j] * cv[r][j] + iv[r][j] * gv;
      hv[j]   = ov * tanh_f(cnew[j]);
    }
    int mg = bm + m;
    *(f32x4*)(cst  + (size_t)mg * H_SZ + bn + nl) = cnew;
    *(f32x4*)(hout + (size_t)mg * H_SZ + bn + nl) = hv;

    // split for next step's A layout (64-row tiles, 256 chunks/tile)
    int nglob = bn + nl;
    int ks2 = nglob >> 5;
    int kc2 = (nglob >> 3) & 3;
    int eb  = nglob & 7;                 // 0 or 4
    int s2  = m * 4 + (kc2 ^ (m & 3));
    size_t ci = (((size_t)mt * 32 + ks2) * 256 + s2) * 8 + eb;
    union { __bf16 b[4]; uint2 u; } uh, ul;
    #pragma unroll
    for (int j = 0; j < 4; ++j) {
      __bf16 hb = (__bf16)hv[j];
      uh.b[j] = hb;
      ul.b[j] = (__bf16)(hv[j] - (float)hb);
    }
    *(uint2*)(ph + ci) = uh.u;
    *(uint2*)(pl + ci) = ul.u;
  }
}

extern "C" void kernel_launch(void* const* d_in, const int* in_sizes, int n_in,
                              void* d_out, int out_size, void* d_ws, size_t ws_size,
                              hipStream_t stream)
{
  const float* x   = (const float*)d_in[0];
  const float* Wih = (const float*)d_in[1];
  const float* Whh = (const float*)d_in[2];
  const float* bih = (const float*)d_in[3];
  const float* bhh = (const float*)d_in[4];
  float* out = (float*)d_out;

  // ws layout (64 MB total):
  float*  xg  = (float*)d_ws;                              // 32 MB
  float*  cst = xg + (size_t)B_SZ * G_SZ;                  //  8 MB
  bf16x8* Wh  = (bf16x8*)(cst + (size_t)B_SZ * H_SZ);      //  8 MB
  bf16x8* hAh = Wh + 524288;                               //  4 MB
  bf16x8* hAl = hAh + 262144;                              //  4 MB
  bf16x8* hBh = hAl + 262144;                              //  4 MB
  bf16x8* hBl = hBh + 262144;                              //  4 MB

  repack_whh<<<2048, 256, 0, stream>>>(Whh, Wh);
  init_h0<<<1024, 256, 0, stream>>>(hAh, hAl);
  xg_gemm<<<dim3(G_SZ / 128, B_SZ / 128), 256, 0, stream>>>(x, Wih, bih, bhh, xg);

  for (int t = 0; t < T_STEPS; ++t) {
    const bf16x8* rh = (t & 1) ? hBh : hAh;
    const bf16x8* rl = (t & 1) ? hBl : hAl;
    bf16x8* wh = (t & 1) ? hAh : hBh;
    bf16x8* wl = (t & 1) ? hAl : hBl;
    lstm_step<<<512, 256, 0, stream>>>(rh, rl, Wh, xg, cst,
                                       out + (size_t)t * B_SZ * H_SZ, wh, wl,
                                       t == 0 ? 1 : 0);
  }
}